// Round 8
// baseline (404.932 us; speedup 1.0000x reference)
//
#include <hip/hip_runtime.h>
#include <hip/hip_bf16.h>
#include <math.h>

// ---------------------------------------------------------------------------
// PMLP_GCN forward:  3x (GEMM -> GCN-agg[+bias]) with BN+ReLU between,
// log_softmax at the end.  N=50000 E=640000 IN=500 HID=128 OUT=64, f32.
// R7: BN stats fused into agg (grid-stride, per-block LDS reduce + atomics);
//     agg outputs f16; norm reads/writes f16. Removes the stats pass and
//     ~51 MB/layer of traffic. GEMM path unchanged from R6 (global_load_lds).
// ---------------------------------------------------------------------------

#define EPS_BN 1e-5f

typedef __attribute__((ext_vector_type(8))) _Float16 f16x8;
typedef __attribute__((ext_vector_type(4))) _Float16 f16x4;
typedef __attribute__((ext_vector_type(2))) _Float16 f16x2;
typedef __attribute__((ext_vector_type(4))) float    f32x4;

__device__ __forceinline__ void gload16(const void* g, void* l) {
    __builtin_amdgcn_global_load_lds(
        (const __attribute__((address_space(1))) void*)g,
        (__attribute__((address_space(3))) void*)l, 16, 0, 0);
}

// ---------------- graph prep ----------------

__global__ void count_k(const int* __restrict__ src, const int* __restrict__ dst,
                        int* __restrict__ cnt, int E) {
    int e = blockIdx.x * 256 + threadIdx.x;
    if (e >= E) return;
    int s = src[e], d = dst[e];
    if (s != d) atomicAdd(&cnt[d], 1);
}

__global__ void prep_k(const int* __restrict__ cnt, float* __restrict__ dinv,
                       float* __restrict__ invdeg, int n) {
    int i = blockIdx.x * 256 + threadIdx.x;
    if (i >= n) return;
    float deg = (float)cnt[i] + 1.0f;   // +1 for added self loop
    dinv[i]   = rsqrtf(deg);
    invdeg[i] = 1.0f / deg;
}

// 3-kernel exclusive prefix scan over cnt[n] -> row_start
__global__ void scan1_k(const int* __restrict__ cnt, int* __restrict__ within,
                        int* __restrict__ btot, int n) {
    __shared__ int s[512];
    int tid = threadIdx.x;
    int i = blockIdx.x * 512 + tid;
    int val = (i < n) ? cnt[i] : 0;
    s[tid] = val;
    __syncthreads();
    for (int off = 1; off < 512; off <<= 1) {
        int v = (tid >= off) ? s[tid - off] : 0;
        __syncthreads();
        s[tid] += v;
        __syncthreads();
    }
    if (i < n) within[i] = s[tid] - val;   // exclusive
    if (tid == 511) btot[blockIdx.x] = s[511];
}

__global__ void scan2_k(const int* __restrict__ btot, int* __restrict__ boff, int nblk) {
    if (threadIdx.x == 0) {
        int run = 0;
        for (int b = 0; b < nblk; ++b) { boff[b] = run; run += btot[b]; }
    }
}

__global__ void scan3_k(const int* __restrict__ within, const int* __restrict__ boff,
                        int* __restrict__ row_start, int* __restrict__ cursor, int n) {
    int i = blockIdx.x * 256 + threadIdx.x;
    if (i >= n) return;
    int v = within[i] + boff[i >> 9];
    row_start[i] = v;
    cursor[i]    = v;
}

__global__ void fill_k(const int* __restrict__ src, const int* __restrict__ dst,
                       const float* __restrict__ dinv, int* __restrict__ cursor,
                       int* __restrict__ eidx, float* __restrict__ ew, int E) {
    int e = blockIdx.x * 256 + threadIdx.x;
    if (e >= E) return;
    int s = src[e], d = dst[e];
    if (s == d) return;
    int pos = atomicAdd(&cursor[d], 1);
    eidx[pos] = s;
    ew[pos]   = dinv[s] * dinv[d];
}

// ---- f32 -> f16 with K padded to Kp (pad zero-filled); used for W and x ----

__global__ void wcvt_k(const float* __restrict__ W, _Float16* __restrict__ Wh,
                       int rows, int K, int Kp) {
    int q = Kp >> 2;
    long long idx = (long long)blockIdx.x * 256 + threadIdx.x;
    if (idx >= (long long)rows * q) return;
    int r = (int)(idx / q), k4 = (int)(idx - (long long)r * q) * 4;
    f16x4 h = {(_Float16)0.f, (_Float16)0.f, (_Float16)0.f, (_Float16)0.f};
    if (k4 < K) {                        // K%4==0 -> all-or-none
        float4 v = *(const float4*)(W + (size_t)r * K + k4);
        h[0] = (_Float16)v.x; h[1] = (_Float16)v.y;
        h[2] = (_Float16)v.z; h[3] = (_Float16)v.w;
    }
    *(f16x4*)(Wh + (size_t)r * Kp + k4) = h;
}

// ---------------- MFMA GEMM: C[M,NC] = A[M,Kp] * Wh[NC,Kp]^T ----------------
// A, Wh f16 (pre-converted, Kp padded with zeros). f32 accumulate, f16 out.
// Block: 256 thr = 4 waves; tile 64 x NC; chunk 64.
// Staging: global_load_lds (16B/lane, 1KB/inst, no VGPR round-trip).
// LDS image: row stride 128B, 16B-slot s of row holds global slot s^(row&7)
// (inverse-swizzled GLOBAL address; LDS dest linear). Fragment ds_read
// applies the same XOR -> 2-way max bank aliasing (free).
// Pipeline: stage(c+1); compute(c); s_waitcnt vmcnt(0); s_barrier.

template <int NC>
__global__ __launch_bounds__(256) void mgemm_k(const _Float16* __restrict__ A,
                                               const _Float16* __restrict__ Wh,
                                               _Float16* __restrict__ C,
                                               int M, int Kp) {
    constexpr int CT = NC / 16;            // col frags per wave
    constexpr int WJ = NC / 32;            // W gload insts per wave
    __shared__ __align__(16) _Float16 As[2][64 * 64];
    __shared__ __align__(16) _Float16 Ws[2][NC * 64];

    const int tid  = threadIdx.x;
    const int lane = tid & 63, wave = tid >> 6;
    const int lrow = lane & 15, kg = lane >> 4;
    const int row0 = blockIdx.x * 64;

    f32x4 acc[CT] = {};

    auto stage = [&](int c0, int b) {
        const int k0 = c0 * 64;
        // A tile: 64 rows x 128B -> 8 insts (2 per wave)
        #pragma unroll
        for (int j = 0; j < 2; ++j) {
            int li  = wave * 128 + j * 64 + lane;      // 0..511
            int row = li >> 3, s = li & 7;
            int gr  = row0 + row;
            int gs  = s ^ (row & 7);
            if (gr < M)
                gload16(A + (size_t)gr * Kp + k0 + gs * 8,
                        (char*)&As[b][0] + (wave * 128 + j * 64) * 16);
        }
        // W tile: NC rows x 128B -> NC/8 insts (WJ per wave)
        #pragma unroll
        for (int j = 0; j < WJ; ++j) {
            int li  = wave * (WJ * 64) + j * 64 + lane;
            int row = li >> 3, s = li & 7;
            int gs  = s ^ (row & 7);
            gload16(Wh + (size_t)row * Kp + k0 + gs * 8,
                    (char*)&Ws[b][0] + (wave * WJ + j) * 1024);
        }
    };

    auto compute = [&](int b) {
        const char* AsB = (const char*)&As[b][0];
        const char* WsB = (const char*)&Ws[b][0];
        #pragma unroll
        for (int ks = 0; ks < 2; ++ks) {
            const int cbase = ks * 64 + kg * 16;       // byte offset in row
            f16x8 af, bf[CT];
            {
                int row = wave * 16 + lrow;
                af = *(const f16x8*)(AsB + row * 128 + (cbase ^ ((row & 7) << 4)));
            }
            #pragma unroll
            for (int ct = 0; ct < CT; ++ct) {
                int row = ct * 16 + lrow;
                bf[ct] = *(const f16x8*)(WsB + row * 128 + (cbase ^ ((row & 7) << 4)));
            }
            #pragma unroll
            for (int ct = 0; ct < CT; ++ct)
                acc[ct] = __builtin_amdgcn_mfma_f32_16x16x32_f16(
                    af, bf[ct], acc[ct], 0, 0, 0);
        }
    };

    const int nchunk = Kp >> 6;            // Kp % 64 == 0
    stage(0, 0);
    asm volatile("s_waitcnt vmcnt(0)" ::: "memory");
    __builtin_amdgcn_s_barrier();
    __builtin_amdgcn_sched_barrier(0);

    for (int c = 0; c < nchunk; ++c) {
        const int b = c & 1;
        if (c + 1 < nchunk) stage(c + 1, b ^ 1);   // loads fly during compute
        compute(b);
        if (c + 1 < nchunk) {
            asm volatile("s_waitcnt vmcnt(0)" ::: "memory");
            __builtin_amdgcn_s_barrier();
            __builtin_amdgcn_sched_barrier(0);
        }
    }

    // ---- epilogue: D lane map col=lane&15, row=(lane>>4)*4+r ----
    #pragma unroll
    for (int r = 0; r < 4; ++r) {
        int grow = row0 + wave * 16 + kg * 4 + r;
        if (grow >= M) continue;
        #pragma unroll
        for (int ct = 0; ct < CT; ++ct)
            C[(size_t)grow * NC + ct * 16 + lrow] = (_Float16)acc[ct][r];
    }
}

// ------------- GCN aggregation + fused BN stats (gather over CSR) -------------
// out[i] = sum_{e: dst=i} w_e * h[src_e] + invdeg[i]*h[i] + bias   (f16 out)
// Grid-stride: 1024 blocks x 4 waves, one node per wave per iter. Each thread
// owns cols (2*lane, 2*lane+1); accumulates (sum, sumsq) in f32 across its
// nodes; block-level LDS reduce across waves -> one atomicAdd set per block.

__global__ void agg128_k(const _Float16* __restrict__ h, const float* __restrict__ invdeg,
                         const int* __restrict__ row_start, const int* __restrict__ cnt,
                         const int* __restrict__ eidx, const float* __restrict__ ew,
                         const float* __restrict__ bias, _Float16* __restrict__ out,
                         float* __restrict__ gsum, float* __restrict__ gsq, int n) {
    const int wv = threadIdx.x >> 6, lane = threadIdx.x & 63;
    const int c = lane * 2;
    const float b0 = bias[c], b1 = bias[c + 1];

    float s0 = 0.f, s1 = 0.f, q0 = 0.f, q1 = 0.f;

    for (int i = blockIdx.x * 4 + wv; i < n; i += gridDim.x * 4) {
        const int st = row_start[i], en = st + cnt[i];
        const float id = invdeg[i];
        f16x2 hv = *(const f16x2*)(h + (size_t)i * 128 + c);
        float a0 = fmaf(id, (float)hv[0], b0);
        float a1 = fmaf(id, (float)hv[1], b1);
        int p = st;
        for (; p + 3 < en; p += 4) {
            int s_0 = eidx[p], s_1 = eidx[p + 1], s_2 = eidx[p + 2], s_3 = eidx[p + 3];
            float w0 = ew[p], w1 = ew[p + 1], w2 = ew[p + 2], w3 = ew[p + 3];
            f16x2 v0 = *(const f16x2*)(h + (size_t)s_0 * 128 + c);
            f16x2 v1 = *(const f16x2*)(h + (size_t)s_1 * 128 + c);
            f16x2 v2 = *(const f16x2*)(h + (size_t)s_2 * 128 + c);
            f16x2 v3 = *(const f16x2*)(h + (size_t)s_3 * 128 + c);
            a0 = fmaf(w0, (float)v0[0], a0); a1 = fmaf(w0, (float)v0[1], a1);
            a0 = fmaf(w1, (float)v1[0], a0); a1 = fmaf(w1, (float)v1[1], a1);
            a0 = fmaf(w2, (float)v2[0], a0); a1 = fmaf(w2, (float)v2[1], a1);
            a0 = fmaf(w3, (float)v3[0], a0); a1 = fmaf(w3, (float)v3[1], a1);
        }
        for (; p < en; ++p) {
            int s_0 = eidx[p]; float w0 = ew[p];
            f16x2 v0 = *(const f16x2*)(h + (size_t)s_0 * 128 + c);
            a0 = fmaf(w0, (float)v0[0], a0); a1 = fmaf(w0, (float)v0[1], a1);
        }
        // stats from pre-rounding f32 values
        s0 += a0; s1 += a1;
        q0 = fmaf(a0, a0, q0); q1 = fmaf(a1, a1, q1);
        f16x2 o; o[0] = (_Float16)a0; o[1] = (_Float16)a1;
        *(f16x2*)(out + (size_t)i * 128 + c) = o;
    }

    // ---- block reduce across the 4 waves (per column pair) ----
    __shared__ float red[4][4][64];      // [quantity][wave][lane]
    red[0][wv][lane] = s0; red[1][wv][lane] = s1;
    red[2][wv][lane] = q0; red[3][wv][lane] = q1;
    __syncthreads();
    if (threadIdx.x < 64) {
        int l = threadIdx.x;
        float t0 = red[0][0][l] + red[0][1][l] + red[0][2][l] + red[0][3][l];
        float t1 = red[1][0][l] + red[1][1][l] + red[1][2][l] + red[1][3][l];
        float u0 = red[2][0][l] + red[2][1][l] + red[2][2][l] + red[2][3][l];
        float u1 = red[3][0][l] + red[3][1][l] + red[3][2][l] + red[3][3][l];
        atomicAdd(&gsum[2 * l],     t0);
        atomicAdd(&gsum[2 * l + 1], t1);
        atomicAdd(&gsq[2 * l],      u0);
        atomicAdd(&gsq[2 * l + 1],  u1);
    }
}

// ---- classifier agg (64 cols) with log_softmax fused (row == wave) ----

__global__ void aggsm_k(const _Float16* __restrict__ h, const float* __restrict__ invdeg,
                        const int* __restrict__ row_start, const int* __restrict__ cnt,
                        const int* __restrict__ eidx, const float* __restrict__ ew,
                        const float* __restrict__ bias, float* __restrict__ out, int n) {
    const int wv = threadIdx.x >> 6, lane = threadIdx.x & 63;
    const int i = blockIdx.x * 4 + wv;
    if (i >= n) return;
    const int st = row_start[i], en = st + cnt[i];
    const float id = invdeg[i];

    float a0 = fmaf(id, (float)h[(size_t)i * 64 + lane], bias[lane]);
    int p = st;
    for (; p + 3 < en; p += 4) {
        int s0 = eidx[p], s1 = eidx[p + 1], s2 = eidx[p + 2], s3 = eidx[p + 3];
        float w0 = ew[p], w1 = ew[p + 1], w2 = ew[p + 2], w3 = ew[p + 3];
        float v0 = (float)h[(size_t)s0 * 64 + lane];
        float v1 = (float)h[(size_t)s1 * 64 + lane];
        float v2 = (float)h[(size_t)s2 * 64 + lane];
        float v3 = (float)h[(size_t)s3 * 64 + lane];
        a0 = fmaf(w0, v0, a0); a0 = fmaf(w1, v1, a0);
        a0 = fmaf(w2, v2, a0); a0 = fmaf(w3, v3, a0);
    }
    for (; p < en; ++p)
        a0 = fmaf(ew[p], (float)h[(size_t)eidx[p] * 64 + lane], a0);

    // fused log_softmax over the 64-wide row held by this wave
    float m = a0;
    #pragma unroll
    for (int d = 32; d >= 1; d >>= 1) m = fmaxf(m, __shfl_xor(m, d, 64));
    float e = __expf(a0 - m);
    float s = e;
    #pragma unroll
    for (int d = 32; d >= 1; d >>= 1) s += __shfl_xor(s, d, 64);
    out[(size_t)i * 64 + lane] = a0 - m - __logf(s);
}

// ---------------- BatchNorm finalize + apply (f16 in/out) ----------------

__global__ void finalize_k(const float* __restrict__ gsum, const float* __restrict__ gsq,
                           float* __restrict__ scale, float* __restrict__ shift, int n) {
    int c = threadIdx.x;   // 128
    float mean = gsum[c] / (float)n;
    float var  = gsq[c] / (float)n - mean * mean;
    float sc   = rsqrtf(var + EPS_BN);
    scale[c] = sc;
    shift[c] = -mean * sc;
}

// BN scale/shift + ReLU, f16 in -> f16 out (16B/lane both ways)
__global__ void norm_k(const _Float16* __restrict__ a, _Float16* __restrict__ o,
                       const float* __restrict__ scale, const float* __restrict__ shift,
                       int total8) {
    int idx = blockIdx.x * 256 + threadIdx.x;
    if (idx >= total8) return;
    f16x8 v = *(const f16x8*)(a + (size_t)idx * 8);
    int c0 = (idx & 15) * 8;
    f16x8 h;
    #pragma unroll
    for (int j = 0; j < 8; ++j)
        h[j] = (_Float16)fmaxf(0.f, fmaf((float)v[j], scale[c0 + j], shift[c0 + j]));
    *(f16x8*)(o + (size_t)idx * 8) = h;
}

// ---------------------------------------------------------------------------

extern "C" void kernel_launch(void* const* d_in, const int* in_sizes, int n_in,
                              void* d_out, int out_size, void* d_ws, size_t ws_size,
                              hipStream_t stream) {
    const float* x  = (const float*)d_in[0];
    const int*   ei = (const int*)d_in[1];
    const float* W0 = (const float*)d_in[2];
    const float* b0 = (const float*)d_in[3];
    const float* W1 = (const float*)d_in[4];
    const float* b1 = (const float*)d_in[5];
    const float* W2 = (const float*)d_in[6];
    const float* b2 = (const float*)d_in[7];

    const int IN = 500;
    const int n = in_sizes[0] / IN;      // 50000
    const int E = in_sizes[1] / 2;       // 640000
    const int* src = ei;
    const int* dst = ei + E;

    // ---- workspace bump allocator (256B aligned) ----
    char* p = (char*)d_ws;
    auto alloc = [&](size_t bytes) -> void* {
        char* r = p;
        p += (bytes + 255) & ~(size_t)255;
        return (void*)r;
    };
    _Float16*  xh      = (_Float16*)alloc((size_t)n * 512 * 2);  // x as f16, K padded
    _Float16*  hb1h    = (_Float16*)alloc((size_t)n * 128 * 2);  // GEMM out / agg in
    _Float16*  hb2a    = (_Float16*)alloc((size_t)n * 128 * 2);  // agg out (f16)
    _Float16*  hb2h    = (_Float16*)alloc((size_t)n * 128 * 2);  // BN out / GEMM in
    _Float16*  W0h     = (_Float16*)alloc((size_t)128 * 512 * 2);
    _Float16*  W1h     = (_Float16*)alloc((size_t)128 * 128 * 2);
    _Float16*  W2h     = (_Float16*)alloc((size_t)64 * 128 * 2);
    int*   deg_cnt  = (int*)alloc((size_t)n * 4);
    float* dinv     = (float*)alloc((size_t)n * 4);
    float* invdeg   = (float*)alloc((size_t)n * 4);
    int*   row_st   = (int*)alloc((size_t)n * 4);
    int*   cursor   = (int*)alloc((size_t)n * 4);
    int*   within   = (int*)alloc((size_t)n * 4);
    int*   btot     = (int*)alloc(256 * 4);
    int*   boff     = (int*)alloc(256 * 4);
    int*   eidx     = (int*)alloc((size_t)E * 4);
    float* ew       = (float*)alloc((size_t)E * 4);
    float* gsum     = (float*)alloc(128 * 4);   // gsum+gsq contiguous: one memset
    float* gsq      = (float*)alloc(128 * 4);
    float* scale    = (float*)alloc(128 * 4);
    float* shift    = (float*)alloc(128 * 4);
    (void)ws_size; (void)n_in; (void)out_size;

    float* out = (float*)d_out;

    const int gE = (E + 255) / 256;
    const int gN = (n + 255) / 256;
    const int nblk = (n + 511) / 512;
    const int gM = (n + 63) / 64;        // 782 blocks
    const int gAgg = 1024;               // grid-stride agg (fused stats)
    const int gA = (n + 3) / 4;          // classifier agg

    // ---- graph prep + f16 conversions (once per call) ----
    hipMemsetAsync(deg_cnt, 0, (size_t)n * 4, stream);
    count_k<<<gE, 256, 0, stream>>>(src, dst, deg_cnt, E);
    prep_k<<<gN, 256, 0, stream>>>(deg_cnt, dinv, invdeg, n);
    scan1_k<<<nblk, 512, 0, stream>>>(deg_cnt, within, btot, n);
    scan2_k<<<1, 64, 0, stream>>>(btot, boff, nblk);
    scan3_k<<<gN, 256, 0, stream>>>(within, boff, row_st, cursor, n);
    fill_k<<<gE, 256, 0, stream>>>(src, dst, dinv, cursor, eidx, ew, E);
    wcvt_k<<<(128 * 512 / 4 + 255) / 256, 256, 0, stream>>>(W0, W0h, 128, 500, 512);
    wcvt_k<<<(128 * 128 / 4 + 255) / 256, 256, 0, stream>>>(W1, W1h, 128, 128, 128);
    wcvt_k<<<(64 * 128 / 4 + 255) / 256, 256, 0, stream>>>(W2, W2h, 64, 128, 128);
    wcvt_k<<<(n * 128 + 255) / 256, 256, 0, stream>>>(x, xh, n, 500, 512);

    // ---- layer 0 ----
    mgemm_k<128><<<gM, 256, 0, stream>>>(xh, W0h, hb1h, n, 512);
    hipMemsetAsync(gsum, 0, 256 * 4, stream);
    agg128_k<<<gAgg, 256, 0, stream>>>(hb1h, invdeg, row_st, deg_cnt, eidx, ew, b0,
                                       hb2a, gsum, gsq, n);
    finalize_k<<<1, 128, 0, stream>>>(gsum, gsq, scale, shift, n);
    norm_k<<<(n * 16 + 255) / 256, 256, 0, stream>>>(hb2a, hb2h, scale, shift, n * 16);

    // ---- layer 1 ----
    mgemm_k<128><<<gM, 256, 0, stream>>>(hb2h, W1h, hb1h, n, 128);
    hipMemsetAsync(gsum, 0, 256 * 4, stream);
    agg128_k<<<gAgg, 256, 0, stream>>>(hb1h, invdeg, row_st, deg_cnt, eidx, ew, b1,
                                       hb2a, gsum, gsq, n);
    finalize_k<<<1, 128, 0, stream>>>(gsum, gsq, scale, shift, n);
    norm_k<<<(n * 16 + 255) / 256, 256, 0, stream>>>(hb2a, hb2h, scale, shift, n * 16);

    // ---- classifier (log_softmax fused into agg) ----
    mgemm_k<64><<<gM, 256, 0, stream>>>(hb2h, W2h, hb1h, n, 128);
    aggsm_k<<<gA, 256, 0, stream>>>(hb1h, invdeg, row_st, deg_cnt, eidx, ew, b2, out, n);
}